// Round 1
// baseline (1503.930 us; speedup 1.0000x reference)
//
#include <hip/hip_runtime.h>
#include <math.h>

// Problem constants
#define B_ROWS 1024
#define D_EMB  1568
#define H_HEADS 16
#define HSZ    98
#define FF_DIM 6272
#define OUT_DIM 784

// ---------------- LayerNorm: one block per row ----------------
__global__ __launch_bounds__(256) void ln_kernel(const float* __restrict__ x,
                                                 const float* __restrict__ g,
                                                 const float* __restrict__ b,
                                                 float* __restrict__ out, int D) {
    const int row = blockIdx.x;
    const float* xr = x + (size_t)row * D;
    float* orow = out + (size_t)row * D;

    float s = 0.f, s2 = 0.f;
    for (int i = threadIdx.x; i < D; i += blockDim.x) {
        float v = xr[i];
        s += v;
        s2 += v * v;
    }
    // wave (64-lane) reduction
    #pragma unroll
    for (int off = 32; off > 0; off >>= 1) {
        s  += __shfl_down(s,  off, 64);
        s2 += __shfl_down(s2, off, 64);
    }
    __shared__ float ws[8], ws2[8];
    const int wave = threadIdx.x >> 6;
    const int lane = threadIdx.x & 63;
    if (lane == 0) { ws[wave] = s; ws2[wave] = s2; }
    __syncthreads();
    if (threadIdx.x == 0) {
        float ts = 0.f, ts2 = 0.f;
        const int nw = blockDim.x >> 6;
        for (int i = 0; i < nw; i++) { ts += ws[i]; ts2 += ws2[i]; }
        ws[0] = ts; ws2[0] = ts2;
    }
    __syncthreads();
    const float mean = ws[0] / (float)D;
    const float var  = ws2[0] / (float)D - mean * mean;
    const float inv  = rsqrtf(var + 1e-5f);
    for (int i = threadIdx.x; i < D; i += blockDim.x) {
        orow[i] = (xr[i] - mean) * inv * g[i] + b[i];
    }
}

// ---------------- Generic tiled fp32 GEMM ----------------
// C[M,N] = A[M,K] @ B + bias, row-major A.
// MODE 0: B is row-major [K,N].
// MODE 1: QKV mapping — column c maps to head=c/98, e=c%98;
//         B element addr = head*K*98 + k*98 + e   (B given as (H,D,98)).
// EPI 0: none. EPI 1: exact GELU.
// Assumes M % 64 == 0 and K % 16 == 0 (true for all calls here); N guarded.
template <int MODE, int EPI>
__global__ __launch_bounds__(256) void gemm_kernel(const float* __restrict__ A,
                                                   const float* __restrict__ Bm,
                                                   const float* __restrict__ bias,
                                                   float* __restrict__ C,
                                                   int M, int N, int K) {
    constexpr int BM = 64, BN = 64, BK = 16;
    __shared__ float As[BK][BM];
    __shared__ float Bs[BK][BN];

    const int tid = threadIdx.x;
    const int tx = tid & 15;       // 0..15 → 4 output cols each
    const int ty = tid >> 4;       // 0..15 → 4 output rows each
    const int m0 = blockIdx.y * BM;
    const int n0 = blockIdx.x * BN;

    // staging assignments
    const int lam = tid >> 2;            // A row within tile 0..63
    const int lak = (tid & 3) << 2;      // A col group 0,4,8,12
    const int lbk = tid >> 4;            // B row within tile 0..15
    const int lbn = (tid & 15) << 2;     // B col group 0..60

    float acc[4][4] = {};

    for (int k0 = 0; k0 < K; k0 += BK) {
        // --- stage A (64x16), float4, store transposed [k][m] ---
        {
            const float4 av = *(const float4*)(A + (size_t)(m0 + lam) * K + (k0 + lak));
            As[lak + 0][lam] = av.x;
            As[lak + 1][lam] = av.y;
            As[lak + 2][lam] = av.z;
            As[lak + 3][lam] = av.w;
        }
        // --- stage B (16x64) ---
        if (MODE == 0) {
            const int c = n0 + lbn;
            if (c + 3 < N) {
                *(float4*)&Bs[lbk][lbn] = *(const float4*)(Bm + (size_t)(k0 + lbk) * N + c);
            } else {
                #pragma unroll
                for (int i = 0; i < 4; i++) {
                    const int cc = c + i;
                    Bs[lbk][lbn + i] = (cc < N) ? Bm[(size_t)(k0 + lbk) * N + cc] : 0.f;
                }
            }
        } else {
            #pragma unroll
            for (int i = 0; i < 4; i++) {
                const int cc = n0 + lbn + i;
                float vv = 0.f;
                if (cc < N) {
                    const int head = cc / HSZ;
                    const int e = cc - head * HSZ;
                    vv = Bm[(size_t)head * K * HSZ + (size_t)(k0 + lbk) * HSZ + e];
                }
                Bs[lbk][lbn + i] = vv;
            }
        }
        __syncthreads();

        #pragma unroll
        for (int kk = 0; kk < BK; kk++) {
            const float4 a4 = *(const float4*)&As[kk][ty << 2];
            const float4 b4 = *(const float4*)&Bs[kk][tx << 2];
            const float ar[4] = {a4.x, a4.y, a4.z, a4.w};
            const float br[4] = {b4.x, b4.y, b4.z, b4.w};
            #pragma unroll
            for (int i = 0; i < 4; i++)
                #pragma unroll
                for (int j = 0; j < 4; j++)
                    acc[i][j] += ar[i] * br[j];
        }
        __syncthreads();
    }

    // --- epilogue ---
    #pragma unroll
    for (int i = 0; i < 4; i++) {
        const int r = m0 + (ty << 2) + i;
        #pragma unroll
        for (int j = 0; j < 4; j++) {
            const int c = n0 + (tx << 2) + j;
            if (c < N) {
                float v = acc[i][j];
                if (bias) v += bias[c];
                if (EPI == 1) v = 0.5f * v * (1.f + erff(v * 0.70710678118654752f));
                C[(size_t)r * N + c] = v;
            }
        }
    }
}

// ---------------- Rank-1 pseudo-attention ----------------
// For each (b,h): out_i = sum_j softmax_j(q_i * k_j * D^-0.5) * v_j
// q,k,v,out all laid out (B, D) with column h*98+e.
__global__ __launch_bounds__(128) void attn_kernel(const float* __restrict__ q,
                                                   const float* __restrict__ k,
                                                   const float* __restrict__ v,
                                                   float* __restrict__ out) {
    const int bh = blockIdx.x;
    const int b = bh / H_HEADS;
    const int h = bh - b * H_HEADS;
    const size_t base = (size_t)b * D_EMB + h * HSZ;

    __shared__ float ks[HSZ], vs[HSZ];
    __shared__ float kmax_s, kmin_s;

    const int t = threadIdx.x;
    if (t < HSZ) {
        ks[t] = k[base + t];
        vs[t] = v[base + t];
    }
    __syncthreads();
    if (t == 0) {
        float mx = -1e30f, mn = 1e30f;
        for (int j = 0; j < HSZ; j++) {
            mx = fmaxf(mx, ks[j]);
            mn = fminf(mn, ks[j]);
        }
        kmax_s = mx;
        kmin_s = mn;
    }
    __syncthreads();
    if (t < HSZ) {
        const float ti = q[base + t] * 0.025253813613805268f;  // 1568^-0.5
        const float m = (ti >= 0.f) ? ti * kmax_s : ti * kmin_s;
        float s = 0.f, acc = 0.f;
        for (int j = 0; j < HSZ; j++) {
            const float e = __expf(ti * ks[j] - m);
            s += e;
            acc += e * vs[j];
        }
        out[base + t] = acc / s;
    }
}

// ---------------- launch ----------------
extern "C" void kernel_launch(void* const* d_in, const int* in_sizes, int n_in,
                              void* d_out, int out_size, void* d_ws, size_t ws_size,
                              hipStream_t stream) {
    const float* x   = (const float*)d_in[0];
    const float* Wq  = (const float*)d_in[1];
    const float* Wk  = (const float*)d_in[2];
    const float* Wv  = (const float*)d_in[3];
    const float* Wo  = (const float*)d_in[4];
    const float* bo  = (const float*)d_in[5];
    const float* g1  = (const float*)d_in[6];
    const float* b1  = (const float*)d_in[7];
    const float* g2  = (const float*)d_in[8];
    const float* b2  = (const float*)d_in[9];
    const float* W1  = (const float*)d_in[10];
    const float* b1f = (const float*)d_in[11];
    const float* W2  = (const float*)d_in[12];
    const float* b2f = (const float*)d_in[13];
    float* out = (float*)d_out;

    const int B = B_ROWS, D = D_EMB, FF = FF_DIM, OD = OUT_DIM;

    float* ws   = (float*)d_ws;
    float* h    = ws;                       // B*D
    float* qb   = h  + (size_t)B * D;       // B*D
    float* kb   = qb + (size_t)B * D;       // B*D
    float* vb   = kb + (size_t)B * D;       // B*D
    float* ff1  = vb + (size_t)B * D;       // B*FF
    float* attnout = h;    // h dead after QKV
    float* proj    = qb;   // q dead after attn
    float* h2      = kb;   // k dead after attn

    // 1. LN1
    ln_kernel<<<B, 256, 0, stream>>>(x, g1, b1, h, D);

    // 2. QKV projections (block-diagonal GEMMs)
    const dim3 gD((D + 63) / 64, B / 64);   // 25 x 16
    gemm_kernel<1, 0><<<gD, 256, 0, stream>>>(h, Wq, nullptr, qb, B, D, D);
    gemm_kernel<1, 0><<<gD, 256, 0, stream>>>(h, Wk, nullptr, kb, B, D, D);
    gemm_kernel<1, 0><<<gD, 256, 0, stream>>>(h, Wv, nullptr, vb, B, D, D);

    // 3. pseudo-attention
    attn_kernel<<<B * H_HEADS, 128, 0, stream>>>(qb, kb, vb, attnout);

    // 4. output projection
    gemm_kernel<0, 0><<<gD, 256, 0, stream>>>(attnout, Wo, bo, proj, B, D, D);

    // 5. LN2
    ln_kernel<<<B, 256, 0, stream>>>(proj, g2, b2, h2, D);

    // 6. MLP up + GELU
    const dim3 gFF(FF / 64, B / 64);        // 98 x 16
    gemm_kernel<0, 1><<<gFF, 256, 0, stream>>>(h2, W1, b1f, ff1, B, FF, D);

    // 7. MLP down -> out
    const dim3 gO((OD + 63) / 64, B / 64);  // 13 x 16
    gemm_kernel<0, 0><<<gO, 256, 0, stream>>>(ff1, W2, b2f, out, B, OD, FF);
}

// Round 3
// 437.528 us; speedup vs baseline: 3.4373x; 3.4373x over previous
//
#include <hip/hip_runtime.h>
#include <math.h>

#define B_ROWS 1024
#define D_EMB  1568
#define H_HEADS 16
#define HSZ    98
#define FF_DIM 6272
#define OUT_DIM 784

typedef unsigned short ushort_t;
typedef __attribute__((ext_vector_type(8))) short short8;
typedef __attribute__((ext_vector_type(4))) float floatx4;

static __device__ __forceinline__ ushort_t f2bf(float f) {
    unsigned int u = __builtin_bit_cast(unsigned int, f);
    u = (u + 0x7fffu + ((u >> 16) & 1u)) >> 16;   // RNE; our values are never NaN
    return (ushort_t)u;
}

// async 16B global -> LDS. dest = wave-uniform base; HW scatters lane*16.
// NOTE: proper addrspacecast (R2 bug: int-truncated flat pointer).
static __device__ __forceinline__ void load16_to_lds(const void* g, void* l) {
    __builtin_amdgcn_global_load_lds(
        (const __attribute__((address_space(1))) void*)g,
        (__attribute__((address_space(3))) void*)l,
        16, 0, 0);
}

// ---------------- LayerNorm: fp32 in -> bf16 out ----------------
__global__ __launch_bounds__(256) void ln_kernel(const float* __restrict__ x,
                                                 const float* __restrict__ g,
                                                 const float* __restrict__ b,
                                                 ushort_t* __restrict__ out, int D) {
    const int row = blockIdx.x;
    const float* xr = x + (size_t)row * D;
    ushort_t* orow = out + (size_t)row * D;

    float s = 0.f, s2 = 0.f;
    for (int i = threadIdx.x; i < D; i += blockDim.x) {
        float v = xr[i];
        s += v; s2 += v * v;
    }
    #pragma unroll
    for (int off = 32; off > 0; off >>= 1) {
        s  += __shfl_down(s,  off, 64);
        s2 += __shfl_down(s2, off, 64);
    }
    __shared__ float ws_[8], ws2_[8];
    const int wave = threadIdx.x >> 6, lane = threadIdx.x & 63;
    if (lane == 0) { ws_[wave] = s; ws2_[wave] = s2; }
    __syncthreads();
    if (threadIdx.x == 0) {
        float ts = 0.f, ts2 = 0.f;
        for (int i = 0; i < 4; i++) { ts += ws_[i]; ts2 += ws2_[i]; }
        ws_[0] = ts; ws2_[0] = ts2;
    }
    __syncthreads();
    const float mean = ws_[0] / (float)D;
    const float var  = ws2_[0] / (float)D - mean * mean;
    const float inv  = rsqrtf(var + 1e-5f);
    for (int i = threadIdx.x; i < D; i += blockDim.x)
        orow[i] = f2bf((xr[i] - mean) * inv * g[i] + b[i]);
}

// ------- weight transpose+convert: fp32 [K][N] -> bf16 [Npad][K], zero-pad rows N..Npad -------
__global__ __launch_bounds__(256) void transpose_plain(const float* __restrict__ src,
                                                       ushort_t* __restrict__ dst,
                                                       int K, int N, int Npad) {
    __shared__ float t[32][33];
    const int n0 = blockIdx.x * 32, k0 = blockIdx.y * 32;
    const int tx = threadIdx.x, ty = threadIdx.y;
    #pragma unroll
    for (int i = 0; i < 4; i++) {
        const int k = k0 + ty + i * 8, n = n0 + tx;
        t[ty + i * 8][tx] = (n < N && k < K) ? src[(size_t)k * N + n] : 0.f;
    }
    __syncthreads();
    #pragma unroll
    for (int i = 0; i < 4; i++) {
        const int n = n0 + ty + i * 8, k = k0 + tx;
        if (n < Npad && k < K) dst[(size_t)n * K + k] = f2bf(t[tx][ty + i * 8]);
    }
}

// QKV: Wq/Wk/Wv (H, K, 98) fp32 -> dst bf16 [4736][K], row n = which*1568 + head*98 + e
// (rows 4704..4735 left unwritten: GEMM reads them but masks those columns on store;
//  0xAA-poison bf16 ≈ -3e-13, numerically harmless)
__global__ __launch_bounds__(256) void transpose_qkv(const float* __restrict__ Wq,
                                                     const float* __restrict__ Wk,
                                                     const float* __restrict__ Wv,
                                                     ushort_t* __restrict__ dst, int K) {
    __shared__ float t[32][33];
    const int which = blockIdx.z >> 4;
    const int head  = blockIdx.z & 15;
    const float* src = (which == 0) ? Wq : (which == 1) ? Wk : Wv;
    src += (size_t)head * K * HSZ;
    const int e0 = blockIdx.x * 32, k0 = blockIdx.y * 32;
    const int tx = threadIdx.x, ty = threadIdx.y;
    #pragma unroll
    for (int i = 0; i < 4; i++) {
        const int k = k0 + ty + i * 8, e = e0 + tx;
        t[ty + i * 8][tx] = (e < HSZ && k < K) ? src[(size_t)k * HSZ + e] : 0.f;
    }
    __syncthreads();
    const int nbase = which * D_EMB + head * HSZ;
    #pragma unroll
    for (int i = 0; i < 4; i++) {
        const int e = e0 + ty + i * 8, k = k0 + tx;
        if (e < HSZ && k < K) dst[(size_t)(nbase + e) * K + k] = f2bf(t[tx][ty + i * 8]);
    }
}

// ---------------- bf16 MFMA GEMM (m97 recipe), fused epilogues ----------------
// A: bf16 [1024][K] row-major.  Bt: bf16 [Npad][K] (k-major).
// MODE 0: direct fp32 store, no bias (QKV).
// MODE 1: direct bf16 store, bias + exact GELU (W1).
// MODE 2: split-K fp32 partials C[z][1024][N] over gridDim.z (Wo, W2).
template <int MODE>
__global__ __launch_bounds__(256) void gemm_bf16(const ushort_t* __restrict__ A,
                                                 const ushort_t* __restrict__ Bt,
                                                 float* __restrict__ C,
                                                 const float* __restrict__ bias,
                                                 int N, int K, int nkTot) {
    __shared__ __align__(16) ushort_t As[128 * 32];
    __shared__ __align__(16) ushort_t Bs[128 * 32];

    const int tid  = threadIdx.x;
    const int wave = tid >> 6, lane = tid & 63;
    const int quad = lane >> 4, l16 = lane & 15;
    const int m0 = blockIdx.y * 128;
    const int n0 = blockIdx.x * 128;
    const int z = blockIdx.z, Z = gridDim.z;
    const int it0 = (int)((long long)nkTot * z / Z);
    const int it1 = (int)((long long)nkTot * (z + 1) / Z);

    const int srow = lane >> 2;          // 0..15
    const int scol = (lane & 3) << 3;    // 0,8,16,24 (k elems)
    const int wm = wave & 1, wn = wave >> 1;

    floatx4 acc[4][4] = {};

    for (int it = it0; it < it1; ++it) {
        const int k0 = it << 5;
        #pragma unroll
        for (int c = 0; c < 2; ++c) {
            const int chunk = wave * 2 + c;          // wave-uniform
            const int row = chunk * 16 + srow;
            load16_to_lds(A  + (size_t)(m0 + row) * K + k0 + scol, &As[chunk * 512]);
            load16_to_lds(Bt + (size_t)(n0 + row) * K + k0 + scol, &Bs[chunk * 512]);
        }
        __syncthreads();

        short8 af[4], bfr[4];
        #pragma unroll
        for (int i = 0; i < 4; i++)
            af[i] = *(const short8*)&As[(wm * 64 + i * 16 + l16) * 32 + quad * 8];
        #pragma unroll
        for (int j = 0; j < 4; j++)
            bfr[j] = *(const short8*)&Bs[(wn * 64 + j * 16 + l16) * 32 + quad * 8];
        #pragma unroll
        for (int i = 0; i < 4; i++)
            #pragma unroll
            for (int j = 0; j < 4; j++)
                acc[i][j] = __builtin_amdgcn_mfma_f32_16x16x32_bf16(af[i], bfr[j], acc[i][j], 0, 0, 0);
        __syncthreads();
    }

    float* Cz = (MODE == 2) ? (C + (size_t)z * B_ROWS * N) : C;
    #pragma unroll
    for (int i = 0; i < 4; i++) {
        const int rbase = m0 + wm * 64 + i * 16 + quad * 4;
        #pragma unroll
        for (int j = 0; j < 4; j++) {
            const int col = n0 + wn * 64 + j * 16 + l16;
            if (col < N) {
                #pragma unroll
                for (int r = 0; r < 4; r++) {
                    float v = acc[i][j][r];
                    if (MODE == 1) {
                        v += bias[col];
                        v = 0.5f * v * (1.f + erff(v * 0.70710678118654752f));
                        ((ushort_t*)Cz)[(size_t)(rbase + r) * N + col] = f2bf(v);
                    } else {
                        Cz[(size_t)(rbase + r) * N + col] = v;
                    }
                }
            }
        }
    }
}

// ---------------- split-K combine + bias ----------------
template <int Z>
__global__ __launch_bounds__(256) void combine_kernel(const float* __restrict__ P,
                                                      const float* __restrict__ bias,
                                                      float* __restrict__ out, int N) {
    const int col = blockIdx.x * 256 + threadIdx.x;
    if (col >= N) return;
    const int row = blockIdx.y;
    const size_t idx = (size_t)row * N + col;
    const size_t stride = (size_t)B_ROWS * N;
    float s = bias[col];
    #pragma unroll
    for (int zz = 0; zz < Z; zz++) s += P[idx + (size_t)zz * stride];
    out[idx] = s;
}

// ---------------- rank-1 pseudo-attention ----------------
// qkv fp32 [B][4704]: q at col h*98+e, k at +1568, v at +3136. out bf16 [B][1568].
__global__ __launch_bounds__(128) void attn_kernel(const float* __restrict__ qkv,
                                                   ushort_t* __restrict__ out) {
    const int bh = blockIdx.x;
    const int b = bh >> 4, h = bh & 15;
    const size_t base = (size_t)b * 4704 + h * HSZ;

    __shared__ float ks[HSZ], vs[HSZ];
    __shared__ float kmax_s, kmin_s;

    const int t = threadIdx.x;
    if (t < HSZ) {
        ks[t] = qkv[base + 1568 + t];
        vs[t] = qkv[base + 3136 + t];
    }
    __syncthreads();
    if (t == 0) {
        float mx = -1e30f, mn = 1e30f;
        for (int j = 0; j < HSZ; j++) { mx = fmaxf(mx, ks[j]); mn = fminf(mn, ks[j]); }
        kmax_s = mx; kmin_s = mn;
    }
    __syncthreads();
    if (t < HSZ) {
        const float ti = qkv[base + t] * 0.025253813613805268f;  // 1568^-0.5
        const float m = (ti >= 0.f) ? ti * kmax_s : ti * kmin_s;
        float s = 0.f, acc = 0.f;
        for (int j = 0; j < HSZ; j++) {
            const float e = __expf(ti * ks[j] - m);
            s += e; acc += e * vs[j];
        }
        out[(size_t)b * D_EMB + h * HSZ + t] = f2bf(acc / s);
    }
}

// ---------------- launch ----------------
// Workspace budget: 48,571,392 B <= 51,380,224 B (R1's proven-safe footprint).
//   R_A [0, 19,670,016):          transposed weights bf16 (max W1^T 19.67 MB)
//   R_B [19,670,016, 38,937,600): qkv fp32 19.27 MB -> Wo partials Z=3 (exact) -> ff1 bf16
//   R_C [38,937,600, 48,571,392): h_bf 3.21 MB + proj 6.42 MB -> W2 partials Z=3 (exact)
extern "C" void kernel_launch(void* const* d_in, const int* in_sizes, int n_in,
                              void* d_out, int out_size, void* d_ws, size_t ws_size,
                              hipStream_t stream) {
    const float* x   = (const float*)d_in[0];
    const float* Wq  = (const float*)d_in[1];
    const float* Wk  = (const float*)d_in[2];
    const float* Wv  = (const float*)d_in[3];
    const float* Wo  = (const float*)d_in[4];
    const float* bo  = (const float*)d_in[5];
    const float* g1  = (const float*)d_in[6];
    const float* b1  = (const float*)d_in[7];
    const float* g2  = (const float*)d_in[8];
    const float* b2  = (const float*)d_in[9];
    const float* W1  = (const float*)d_in[10];
    const float* b1f = (const float*)d_in[11];
    const float* W2  = (const float*)d_in[12];
    const float* b2f = (const float*)d_in[13];
    float* out = (float*)d_out;

    char* w = (char*)d_ws;
    ushort_t* Wt    = (ushort_t*)(w);                    // R_A
    char*     RB    = w + 19670016;                      // R_B
    char*     RC    = w + 38937600;                      // R_C

    float*    qkv   = (float*)RB;        // 1024x4704 fp32
    float*    PpB   = (float*)RB;        // Wo partials Z=3 (qkv dead)
    ushort_t* ff1   = (ushort_t*)RB;     // 1024x6272 bf16 (partials dead)
    ushort_t* h_bf  = (ushort_t*)RC;     // LN1 out -> attn out -> LN2 out (serial)
    float*    proj  = (float*)(RC + 3211264);
    float*    PpC   = (float*)RC;        // W2 partials Z=3 (h_bf, proj dead)

    const dim3 tb(32, 8);

    // 1. LN1 -> h_bf
    ln_kernel<<<B_ROWS, 256, 0, stream>>>(x, g1, b1, h_bf, D_EMB);

    // 2. QKV: transpose + fused GEMM (direct fp32), 296 blocks
    transpose_qkv<<<dim3(4, 49, 48), tb, 0, stream>>>(Wq, Wk, Wv, Wt, D_EMB);
    gemm_bf16<0><<<dim3(37, 8, 1), 256, 0, stream>>>(h_bf, Wt, qkv, nullptr, 4704, D_EMB, 49);

    // 3. attention -> h_bf (LN1 out dead)
    attn_kernel<<<B_ROWS * H_HEADS, 128, 0, stream>>>(qkv, h_bf);

    // 4. Wo: transpose [1664][1568] + split-K Z=3 (312 blocks) + combine(+bo) -> proj
    transpose_plain<<<dim3(52, 49), tb, 0, stream>>>(Wo, Wt, D_EMB, D_EMB, 1664);
    gemm_bf16<2><<<dim3(13, 8, 3), 256, 0, stream>>>(h_bf, Wt, PpB, nullptr, D_EMB, D_EMB, 49);
    combine_kernel<3><<<dim3(7, B_ROWS), 256, 0, stream>>>(PpB, bo, proj, D_EMB);

    // 5. LN2 -> h_bf (attn out dead)
    ln_kernel<<<B_ROWS, 256, 0, stream>>>(proj, g2, b2, h_bf, D_EMB);

    // 6. W1: transpose [6272][1568] + fused GEMM (bias+GELU -> bf16 ff1), 392 blocks
    transpose_plain<<<dim3(196, 49), tb, 0, stream>>>(W1, Wt, D_EMB, FF_DIM, FF_DIM);
    gemm_bf16<1><<<dim3(49, 8, 1), 256, 0, stream>>>(h_bf, Wt, (float*)ff1, b1f, FF_DIM, D_EMB, 49);

    // 7. W2: transpose [896][6272] + split-K Z=3 (168 blocks) + combine(+b2f) -> out
    transpose_plain<<<dim3(28, 196), tb, 0, stream>>>(W2, Wt, FF_DIM, OUT_DIM, 896);
    gemm_bf16<2><<<dim3(7, 8, 3), 256, 0, stream>>>(ff1, Wt, PpC, nullptr, OUT_DIM, FF_DIM, 196);
    combine_kernel<3><<<dim3(4, B_ROWS), 256, 0, stream>>>(PpC, b2f, out, OUT_DIM);
}

// Round 4
// 383.683 us; speedup vs baseline: 3.9197x; 1.1403x over previous
//
#include <hip/hip_runtime.h>
#include <math.h>

#define B_ROWS 1024
#define D_EMB  1568
#define H_HEADS 16
#define HSZ    98
#define FF_DIM 6272
#define OUT_DIM 784

typedef unsigned short ushort_t;
typedef __attribute__((ext_vector_type(8))) short short8;
typedef __attribute__((ext_vector_type(4))) float floatx4;

static __device__ __forceinline__ ushort_t f2bf(float f) {
    unsigned int u = __builtin_bit_cast(unsigned int, f);
    u = (u + 0x7fffu + ((u >> 16) & 1u)) >> 16;   // RNE; our values are never NaN
    return (ushort_t)u;
}

// async 16B global -> LDS. dest = wave-uniform base; HW scatters lane*16.
static __device__ __forceinline__ void load16_to_lds(const void* g, void* l) {
    __builtin_amdgcn_global_load_lds(
        (const __attribute__((address_space(1))) void*)g,
        (__attribute__((address_space(3))) void*)l,
        16, 0, 0);
}

// ---------------- LayerNorm: fp32 in -> bf16 out ----------------
__global__ __launch_bounds__(256) void ln_kernel(const float* __restrict__ x,
                                                 const float* __restrict__ g,
                                                 const float* __restrict__ b,
                                                 ushort_t* __restrict__ out, int D) {
    const int row = blockIdx.x;
    const float* xr = x + (size_t)row * D;
    ushort_t* orow = out + (size_t)row * D;

    float s = 0.f, s2 = 0.f;
    for (int i = threadIdx.x; i < D; i += blockDim.x) {
        float v = xr[i];
        s += v; s2 += v * v;
    }
    #pragma unroll
    for (int off = 32; off > 0; off >>= 1) {
        s  += __shfl_down(s,  off, 64);
        s2 += __shfl_down(s2, off, 64);
    }
    __shared__ float ws_[8], ws2_[8];
    const int wave = threadIdx.x >> 6, lane = threadIdx.x & 63;
    if (lane == 0) { ws_[wave] = s; ws2_[wave] = s2; }
    __syncthreads();
    if (threadIdx.x == 0) {
        float ts = 0.f, ts2 = 0.f;
        for (int i = 0; i < 4; i++) { ts += ws_[i]; ts2 += ws2_[i]; }
        ws_[0] = ts; ws2_[0] = ts2;
    }
    __syncthreads();
    const float mean = ws_[0] / (float)D;
    const float var  = ws2_[0] / (float)D - mean * mean;
    const float inv  = rsqrtf(var + 1e-5f);
    for (int i = threadIdx.x; i < D; i += blockDim.x)
        orow[i] = f2bf((xr[i] - mean) * inv * g[i] + b[i]);
}

// ------- weight transpose+convert: fp32 [K][N] -> bf16 [Npad][K], zero rows N..Npad -------
__global__ __launch_bounds__(256) void transpose_plain(const float* __restrict__ src,
                                                       ushort_t* __restrict__ dst,
                                                       int K, int N, int Npad) {
    __shared__ float t[32][33];
    const int n0 = blockIdx.x * 32, k0 = blockIdx.y * 32;
    const int tx = threadIdx.x, ty = threadIdx.y;
    #pragma unroll
    for (int i = 0; i < 4; i++) {
        const int k = k0 + ty + i * 8, n = n0 + tx;
        t[ty + i * 8][tx] = (n < N && k < K) ? src[(size_t)k * N + n] : 0.f;
    }
    __syncthreads();
    #pragma unroll
    for (int i = 0; i < 4; i++) {
        const int n = n0 + ty + i * 8, k = k0 + tx;
        if (n < Npad && k < K) dst[(size_t)n * K + k] = f2bf(t[tx][ty + i * 8]);
    }
}

// QKV: Wq/Wk/Wv (H, K, 98) fp32 -> dst bf16 [4736][K], row n = which*1568 + head*98 + e
// (rows 4704..4735 unwritten: GEMM reads them but masks those columns on store;
//  0xAA-poison bf16 ≈ -3e-13, harmless in masked-out columns)
__global__ __launch_bounds__(256) void transpose_qkv(const float* __restrict__ Wq,
                                                     const float* __restrict__ Wk,
                                                     const float* __restrict__ Wv,
                                                     ushort_t* __restrict__ dst, int K) {
    __shared__ float t[32][33];
    const int which = blockIdx.z >> 4;
    const int head  = blockIdx.z & 15;
    const float* src = (which == 0) ? Wq : (which == 1) ? Wk : Wv;
    src += (size_t)head * K * HSZ;
    const int e0 = blockIdx.x * 32, k0 = blockIdx.y * 32;
    const int tx = threadIdx.x, ty = threadIdx.y;
    #pragma unroll
    for (int i = 0; i < 4; i++) {
        const int k = k0 + ty + i * 8, e = e0 + tx;
        t[ty + i * 8][tx] = (e < HSZ && k < K) ? src[(size_t)k * HSZ + e] : 0.f;
    }
    __syncthreads();
    const int nbase = which * D_EMB + head * HSZ;
    #pragma unroll
    for (int i = 0; i < 4; i++) {
        const int e = e0 + ty + i * 8, k = k0 + tx;
        if (e < HSZ && k < K) dst[(size_t)(nbase + e) * K + k] = f2bf(t[tx][ty + i * 8]);
    }
}

// ---------------- bf16 MFMA GEMM, 64x128x32 tile (R4: 2x blocks vs 128x128) ----------------
// A: bf16 [1024][K] row-major.  Bt: bf16 [Npad][K] (k-major).
// Grid: x = m-tile (16, fastest -> blocks sharing a B-tile co-dispatch), y = n-tile, z = split-K.
// 4 waves; wave w computes C rows 0..63 x cols w*32..w*32+31 (4x2 frags of 16x16).
// MODE 0: direct fp32 store. MODE 1: direct bf16 store, bias+GELU. MODE 2: split-K partials.
template <int MODE>
__global__ __launch_bounds__(256) void gemm_bf16(const ushort_t* __restrict__ A,
                                                 const ushort_t* __restrict__ Bt,
                                                 float* __restrict__ C,
                                                 const float* __restrict__ bias,
                                                 int N, int K, int nkTot) {
    __shared__ __align__(16) ushort_t As[64 * 32];
    __shared__ __align__(16) ushort_t Bs[128 * 32];

    const int tid  = threadIdx.x;
    const int wave = tid >> 6, lane = tid & 63;
    const int quad = lane >> 4, l16 = lane & 15;
    const int m0 = blockIdx.x * 64;
    const int n0 = blockIdx.y * 128;
    const int z = blockIdx.z, Z = gridDim.z;
    const int it0 = (int)((long long)nkTot * z / Z);
    const int it1 = (int)((long long)nkTot * (z + 1) / Z);

    const int srow = lane >> 2;          // 0..15
    const int scol = (lane & 3) << 3;    // 0,8,16,24 (k elems)

    floatx4 acc[4][2] = {};

    for (int it = it0; it < it1; ++it) {
        const int k0 = it << 5;
        // A: 64x32 = 4KB, one 16-row chunk per wave
        load16_to_lds(A + (size_t)(m0 + wave * 16 + srow) * K + k0 + scol,
                      &As[wave * 512]);
        // B: 128x32 = 8KB, two 16-row chunks per wave
        #pragma unroll
        for (int c = 0; c < 2; ++c) {
            const int row = wave * 32 + c * 16 + srow;
            load16_to_lds(Bt + (size_t)(n0 + row) * K + k0 + scol,
                          &Bs[(wave * 2 + c) * 512]);
        }
        __syncthreads();

        short8 af[4], bfr[2];
        #pragma unroll
        for (int i = 0; i < 4; i++)
            af[i] = *(const short8*)&As[(i * 16 + l16) * 32 + quad * 8];
        #pragma unroll
        for (int j = 0; j < 2; j++)
            bfr[j] = *(const short8*)&Bs[(wave * 32 + j * 16 + l16) * 32 + quad * 8];
        #pragma unroll
        for (int i = 0; i < 4; i++)
            #pragma unroll
            for (int j = 0; j < 2; j++)
                acc[i][j] = __builtin_amdgcn_mfma_f32_16x16x32_bf16(af[i], bfr[j], acc[i][j], 0, 0, 0);
        __syncthreads();
    }

    float* Cz = (MODE == 2) ? (C + (size_t)z * B_ROWS * N) : C;
    #pragma unroll
    for (int i = 0; i < 4; i++) {
        const int rbase = m0 + i * 16 + quad * 4;
        #pragma unroll
        for (int j = 0; j < 2; j++) {
            const int col = n0 + wave * 32 + j * 16 + l16;
            if (col < N) {
                #pragma unroll
                for (int r = 0; r < 4; r++) {
                    float v = acc[i][j][r];
                    if (MODE == 1) {
                        v += bias[col];
                        v = 0.5f * v * (1.f + erff(v * 0.70710678118654752f));
                        ((ushort_t*)Cz)[(size_t)(rbase + r) * N + col] = f2bf(v);
                    } else {
                        Cz[(size_t)(rbase + r) * N + col] = v;
                    }
                }
            }
        }
    }
}

// ---------------- split-K combine + bias (plain, fp32 out) ----------------
template <int Z>
__global__ __launch_bounds__(256) void combine_kernel(const float* __restrict__ P,
                                                      const float* __restrict__ bias,
                                                      float* __restrict__ out, int N) {
    const int col = blockIdx.x * 256 + threadIdx.x;
    if (col >= N) return;
    const int row = blockIdx.y;
    const size_t idx = (size_t)row * N + col;
    const size_t stride = (size_t)B_ROWS * N;
    float s = bias[col];
    #pragma unroll
    for (int zz = 0; zz < Z; zz++) s += P[idx + (size_t)zz * stride];
    out[idx] = s;
}

// -------- fused: split-K combine + bias + LayerNorm -> bf16 (one block per row) --------
template <int Z>
__global__ __launch_bounds__(256) void combine_ln_kernel(const float* __restrict__ P,
                                                         const float* __restrict__ bias,
                                                         const float* __restrict__ g,
                                                         const float* __restrict__ b,
                                                         ushort_t* __restrict__ out, int N) {
    __shared__ float t[D_EMB];
    __shared__ float ws_[8], ws2_[8];
    const int row = blockIdx.x;
    const size_t stride = (size_t)B_ROWS * N;
    const float* Pr = P + (size_t)row * N;

    float s = 0.f, s2 = 0.f;
    for (int i = threadIdx.x; i < N; i += blockDim.x) {
        float v = bias[i];
        #pragma unroll
        for (int zz = 0; zz < Z; zz++) v += Pr[i + (size_t)zz * stride];
        t[i] = v;
        s += v; s2 += v * v;
    }
    #pragma unroll
    for (int off = 32; off > 0; off >>= 1) {
        s  += __shfl_down(s,  off, 64);
        s2 += __shfl_down(s2, off, 64);
    }
    const int wave = threadIdx.x >> 6, lane = threadIdx.x & 63;
    if (lane == 0) { ws_[wave] = s; ws2_[wave] = s2; }
    __syncthreads();
    if (threadIdx.x == 0) {
        float ts = 0.f, ts2 = 0.f;
        for (int i = 0; i < 4; i++) { ts += ws_[i]; ts2 += ws2_[i]; }
        ws_[0] = ts; ws2_[0] = ts2;
    }
    __syncthreads();
    const float mean = ws_[0] / (float)N;
    const float var  = ws2_[0] / (float)N - mean * mean;
    const float inv  = rsqrtf(var + 1e-5f);
    ushort_t* orow = out + (size_t)row * N;
    for (int i = threadIdx.x; i < N; i += blockDim.x)
        orow[i] = f2bf((t[i] - mean) * inv * g[i] + b[i]);
}

// ---------------- rank-1 pseudo-attention ----------------
// qkv fp32 [B][4704]: q at col h*98+e, k at +1568, v at +3136. out bf16 [B][1568].
__global__ __launch_bounds__(128) void attn_kernel(const float* __restrict__ qkv,
                                                   ushort_t* __restrict__ out) {
    const int bh = blockIdx.x;
    const int b = bh >> 4, h = bh & 15;
    const size_t base = (size_t)b * 4704 + h * HSZ;

    __shared__ float ks[HSZ], vs[HSZ];
    __shared__ float kmax_s, kmin_s;

    const int t = threadIdx.x;
    if (t < HSZ) {
        ks[t] = qkv[base + 1568 + t];
        vs[t] = qkv[base + 3136 + t];
    }
    __syncthreads();
    if (t == 0) {
        float mx = -1e30f, mn = 1e30f;
        for (int j = 0; j < HSZ; j++) { mx = fmaxf(mx, ks[j]); mn = fminf(mn, ks[j]); }
        kmax_s = mx; kmin_s = mn;
    }
    __syncthreads();
    if (t < HSZ) {
        const float ti = qkv[base + t] * 0.025253813613805268f;  // 1568^-0.5
        const float m = (ti >= 0.f) ? ti * kmax_s : ti * kmin_s;
        float s = 0.f, acc = 0.f;
        for (int j = 0; j < HSZ; j++) {
            const float e = __expf(ti * ks[j] - m);
            s += e; acc += e * vs[j];
        }
        out[(size_t)b * D_EMB + h * HSZ + t] = f2bf(acc / s);
    }
}

// ---------------- launch ----------------
// Workspace map (peak 51,330,048 B <= 51,380,224 proven-safe):
//   R_A [0, 19,670,016):          transposed weights bf16 (max W1t 19.669 MB)
//   R_B [19,670,016, 38,937,600): qkv fp32 19.27 MB -> Wo partials Z=3 (19.27 MB, exact)
//                                 -> ff1 bf16 12.85 MB
//   R_C [38,937,600, 51,380,224): h_bf 3.21 MB (LN1 out -> attn out -> LN2 out, serial)
//   W2 partials Z=5 (16.06 MB) at [32,515,072, 48,571,392): RB tail (ff1 ends at
//   +12,845,056) + all of R_C — h_bf dead after W1 GEMM; contiguous since RB|RC adjoin.
extern "C" void kernel_launch(void* const* d_in, const int* in_sizes, int n_in,
                              void* d_out, int out_size, void* d_ws, size_t ws_size,
                              hipStream_t stream) {
    const float* x   = (const float*)d_in[0];
    const float* Wq  = (const float*)d_in[1];
    const float* Wk  = (const float*)d_in[2];
    const float* Wv  = (const float*)d_in[3];
    const float* Wo  = (const float*)d_in[4];
    const float* bo  = (const float*)d_in[5];
    const float* g1  = (const float*)d_in[6];
    const float* b1  = (const float*)d_in[7];
    const float* g2  = (const float*)d_in[8];
    const float* b2  = (const float*)d_in[9];
    const float* W1  = (const float*)d_in[10];
    const float* b1f = (const float*)d_in[11];
    const float* W2  = (const float*)d_in[12];
    const float* b2f = (const float*)d_in[13];
    float* out = (float*)d_out;

    char* w = (char*)d_ws;
    ushort_t* Wt   = (ushort_t*)(w);                  // R_A
    char*     RB   = w + 19670016;                    // R_B
    char*     RC   = w + 38937600;                    // R_C

    float*    qkv  = (float*)RB;                      // 1024x4704 fp32
    float*    PpB  = (float*)RB;                      // Wo partials Z=3 (qkv dead)
    ushort_t* ff1  = (ushort_t*)RB;                   // 1024x6272 bf16 (partials dead)
    ushort_t* h_bf = (ushort_t*)RC;                   // serial LN1/attn/LN2 buffer
    float*    PpC  = (float*)(w + 32515072);          // W2 partials Z=5 (h_bf, ff1-tail dead)

    const dim3 tb(32, 8);

    // 1. LN1 -> h_bf
    ln_kernel<<<B_ROWS, 256, 0, stream>>>(x, g1, b1, h_bf, D_EMB);

    // 2. QKV: transpose + GEMM (direct fp32), grid 16x37 = 592 blocks
    transpose_qkv<<<dim3(4, 49, 48), tb, 0, stream>>>(Wq, Wk, Wv, Wt, D_EMB);
    gemm_bf16<0><<<dim3(16, 37, 1), 256, 0, stream>>>(h_bf, Wt, qkv, nullptr, 4704, D_EMB, 49);

    // 3. attention -> h_bf (LN1 out dead)
    attn_kernel<<<B_ROWS * H_HEADS, 128, 0, stream>>>(qkv, h_bf);

    // 4. Wo: transpose [1664][1568]; split-K Z=3, grid 16x13x3 = 624 blocks;
    //    fused combine+bias+LN2 -> h_bf (attn out consumed by GEMM before combine runs)
    transpose_plain<<<dim3(52, 49), tb, 0, stream>>>(Wo, Wt, D_EMB, D_EMB, 1664);
    gemm_bf16<2><<<dim3(16, 13, 3), 256, 0, stream>>>(h_bf, Wt, PpB, nullptr, D_EMB, D_EMB, 49);
    combine_ln_kernel<3><<<B_ROWS, 256, 0, stream>>>(PpB, bo, g2, b2, h_bf, D_EMB);

    // 5. W1: transpose [6272][1568]; GEMM (bias+GELU -> bf16 ff1), grid 16x49 = 784 blocks
    transpose_plain<<<dim3(196, 49), tb, 0, stream>>>(W1, Wt, D_EMB, FF_DIM, FF_DIM);
    gemm_bf16<1><<<dim3(16, 49, 1), 256, 0, stream>>>(h_bf, Wt, (float*)ff1, b1f, FF_DIM, D_EMB, 49);

    // 6. W2: transpose [896][6272]; split-K Z=5, grid 16x7x5 = 560 blocks; combine -> out
    transpose_plain<<<dim3(28, 196), tb, 0, stream>>>(W2, Wt, FF_DIM, OUT_DIM, 896);
    gemm_bf16<2><<<dim3(16, 7, 5), 256, 0, stream>>>(ff1, Wt, PpC, nullptr, OUT_DIM, FF_DIM, 196);
    combine_kernel<5><<<dim3(4, B_ROWS), 256, 0, stream>>>(PpC, b2f, out, OUT_DIM);
}